// Round 12
// baseline (194.252 us; speedup 1.0000x reference)
//
#include <hip/hip_runtime.h>

typedef __bf16 bf16_t;
typedef __bf16 bf16x4_t __attribute__((ext_vector_type(4)));
typedef __bf16 bf16x8 __attribute__((ext_vector_type(8)));
typedef float f32x4 __attribute__((ext_vector_type(4)));

#define NH 8
#define DH 32
#define QL 256
#define KL 256
#define CIN 64
#define HD 256  // NH*DH

__device__ __forceinline__ bf16_t f2bf(float x) { return (bf16_t)x; }

__device__ __forceinline__ f32x4 mfma16(bf16x8 a, bf16x8 b, f32x4 c) {
    return __builtin_amdgcn_mfma_f32_16x16x32_bf16(a, b, c, 0, 0, 0);
}

__device__ __forceinline__ bf16x8 cvt8(const float* __restrict__ p) {
    const f32x4 lo = *(const f32x4*)p;
    const f32x4 hi = *(const f32x4*)(p + 4);
    bf16x8 r;
#pragma unroll
    for (int j = 0; j < 4; ++j) { r[j] = f2bf(lo[j]); r[4 + j] = f2bf(hi[j]); }
    return r;
}

// ---------------------------------------------------------------------------
// Phase 1: projection as 3072 one-wave tile-task blocks (attn3's proven
// shape: tiny barrier-free blocks, high TLP — r11 lesson: proj_v2's 4-wave
// barrier-coupled serial-chain blocks were the real ~85 µs bottleneck).
// b = which*1024 + h*128 + s (s fastest -> all of an s's 24 blocks on one
// XCD; X slice L2-resident). W B-frags: 32 independent scalar gathers,
// amortized over 16 tiles. Double-buffered 5 KB LDS transpose.
//   Qf/Kf per (s,h): 16 tiles x [lane][8], elem = M[tile*16+l16][quad*8+j]
//   Vf  per (s,h): 16 chunks x [lane][8],  elem = V[cs*32+quad*8+j][nt*16+l16]
//   WoF: (h*4+nt) x [lane][8], elem = Wo[h*32+quad*8+j][nt*16+l16]
__launch_bounds__(64, 4)
__global__ void projt(const float* __restrict__ Xq, const float* __restrict__ Xkv,
                      const float* __restrict__ Wq, const float* __restrict__ Wk,
                      const float* __restrict__ Wv, const float* __restrict__ Wo,
                      bf16_t* __restrict__ Qf, bf16_t* __restrict__ Kf,
                      bf16_t* __restrict__ Vf, bf16_t* __restrict__ WoF) {
    const int b = blockIdx.x;
    const int s = b & 127, h = (b >> 7) & 7, which = b >> 10;  // 0=Q 1=K 2=V
    const int lane = threadIdx.x & 63;
    const int quad = lane >> 4, l16 = lane & 15;
    const f32x4 vzero = {0.f, 0.f, 0.f, 0.f};

    __shared__ __attribute__((aligned(16))) bf16_t sT[2][32][40];  // 5 KB dbuf

    const float* __restrict__ X = (which == 0) ? Xq : Xkv;
    const float* __restrict__ W = (which == 0) ? Wq : (which == 1 ? Wk : Wv);
    const float scale = (which == 0) ? 0.17677669529663687f : 1.0f;  // 1/sqrt(32)

    // W B-frags via scalar gathers (independent, L2-hot: shared by 128 s-blocks)
    // bw[nt][ks][j] = W[(ks*32+quad*8+j)][h*32+nt*16+l16]
    bf16x8 bw[2][2];
#pragma unroll
    for (int nt = 0; nt < 2; ++nt)
#pragma unroll
        for (int ks = 0; ks < 2; ++ks) {
            bf16x8 f;
#pragma unroll
            for (int j = 0; j < 8; ++j)
                f[j] = f2bf(W[(ks * 32 + quad * 8 + j) * HD + h * DH + nt * 16 + l16]);
            bw[nt][ks] = f;
        }

    // 8 special blocks also emit Wo fragment-native (32 extra gathers)
    if (which == 1 && s == 0 && WoF != nullptr) {
#pragma unroll
        for (int nt = 0; nt < 4; ++nt) {
            bf16x8 f;
#pragma unroll
            for (int j = 0; j < 8; ++j)
                f[j] = f2bf(Wo[(h * DH + quad * 8 + j) * CIN + nt * 16 + l16]);
            *(bf16x8*)&WoF[(size_t)(h * 4 + nt) * 512 + lane * 8] = f;
        }
    }

    const size_t base = (size_t)(s * NH + h) * 8192;

    if (which < 2) {
        bf16_t* __restrict__ Dst = which ? Kf : Qf;
        // 16 independent tile tasks; unroll 2 + LDS dbuf for chain overlap
#pragma unroll 2
        for (int mt = 0; mt < 16; ++mt) {
            const float* xp = &X[(s * QL + mt * 16 + l16) * CIN + quad * 8];
            const bf16x8 a0 = cvt8(xp);
            const bf16x8 a1 = cvt8(xp + 32);
            f32x4 c0 = vzero, c1 = vzero;
            c0 = mfma16(a0, bw[0][0], c0);
            c0 = mfma16(a1, bw[0][1], c0);
            c1 = mfma16(a0, bw[1][0], c1);
            c1 = mfma16(a1, bw[1][1], c1);
            // C/D (row=quad*4+r, d=nt*16+l16) -> sT -> A-frag (same-wave RT)
#pragma unroll
            for (int nt = 0; nt < 2; ++nt) {
                const f32x4 c = nt ? c1 : c0;
#pragma unroll
                for (int r = 0; r < 4; ++r)
                    sT[mt & 1][quad * 4 + r][nt * 16 + l16] = f2bf(c[r] * scale);
            }
            const bf16x8 frag = *(const bf16x8*)&sT[mt & 1][l16][quad * 8];
            *(bf16x8*)&Dst[base + (size_t)mt * 512 + lane * 8] = frag;
        }
    } else {
        // 8 independent 32-kv chunk tasks
#pragma unroll 2
        for (int cs = 0; cs < 8; ++cs) {
            bf16x8 a[2][2];
#pragma unroll
            for (int u = 0; u < 2; ++u) {
                const float* xp = &Xkv[(s * KL + cs * 32 + u * 16 + l16) * CIN + quad * 8];
                a[u][0] = cvt8(xp);
                a[u][1] = cvt8(xp + 32);
            }
            // C/D (kv=u*16+quad*4+r, d=nth*16+l16) -> sT[d][kv] (transposed)
#pragma unroll
            for (int u = 0; u < 2; ++u)
#pragma unroll
                for (int nth = 0; nth < 2; ++nth) {
                    f32x4 c = mfma16(a[u][0], bw[nth][0], vzero);
                    c = mfma16(a[u][1], bw[nth][1], c);
#pragma unroll
                    for (int r = 0; r < 4; ++r)
                        sT[cs & 1][nth * 16 + l16][u * 16 + quad * 4 + r] = f2bf(c[r]);
                }
#pragma unroll
            for (int nt = 0; nt < 2; ++nt) {
                const bf16x8 frag = *(const bf16x8*)&sT[cs & 1][nt * 16 + l16][quad * 8];
                *(bf16x8*)&Vf[base + (size_t)(cs * 2 + nt) * 512 + lane * 8] = frag;
            }
        }
    }
}

// ---------------------------------------------------------------------------
// Phase 2: attention, barrier-free pure consumer (r7/r9-proven structure).
// (256,6): 85-VGPR budget >= the 56 this kernel uses (r8's spill was a
// 64-budget) -> 24 waves/CU vs r9's 16.
__launch_bounds__(256, 6)
__global__ void attn3(const float* __restrict__ Mask, const float* __restrict__ Bias,
                      const bf16_t* __restrict__ Qf, const bf16_t* __restrict__ Kf,
                      const bf16_t* __restrict__ Vf, bf16_t* __restrict__ Ows) {
    const int s = blockIdx.x, qt = blockIdx.y, h = blockIdx.z;
    const int tid = threadIdx.x, lane = tid & 63, w = tid >> 6;
    const int quad = lane >> 4, l16 = lane & 15;
    const f32x4 vzero = {0.f, 0.f, 0.f, 0.f};

    __shared__ __attribute__((aligned(16))) bf16_t sPT[4][16][136];  // 17.4 KB

    const int tile = qt * 4 + w, q0 = tile * 16;
    const size_t base = (size_t)(s * NH + h) * 8192;

    const bf16x8 qfr = *(const bf16x8*)&Qf[base + (size_t)tile * 512 + lane * 8];

    // sv = bias + mask (loads issue early), then S' = K·Q^T on top (C operand)
    f32x4 sv[16];
    const float* bbase = &Bias[(size_t)(h * QL + q0 + l16) * KL];
    const float* mbase = &Mask[s * KL];
#pragma unroll
    for (int ct = 0; ct < 16; ++ct) {
        const f32x4 b4 = *(const f32x4*)&bbase[ct * 16 + quad * 4];
        const f32x4 m4 = *(const f32x4*)&mbase[ct * 16 + quad * 4];
        sv[ct] = b4 + (m4 - 1.0f) * 1.0e9f;
    }
#pragma unroll
    for (int ct = 0; ct < 16; ++ct) {
        const bf16x8 ak = *(const bf16x8*)&Kf[base + ct * 512 + lane * 8];
        sv[ct] = mfma16(ak, qfr, sv[ct]);  // C/D row=kv-local, col=q
    }
    // softmax over kv: per-lane 64 values + xor 16/32 across quads
    float mx = -1e30f;
#pragma unroll
    for (int ct = 0; ct < 16; ++ct)
#pragma unroll
        for (int r = 0; r < 4; ++r) mx = fmaxf(mx, sv[ct][r]);
    mx = fmaxf(mx, __shfl_xor(mx, 16, 64));
    mx = fmaxf(mx, __shfl_xor(mx, 32, 64));
    float sum = 0.f;
#pragma unroll
    for (int ct = 0; ct < 16; ++ct)
#pragma unroll
        for (int r = 0; r < 4; ++r) {
            const float e = __expf(sv[ct][r] - mx);
            sv[ct][r] = e;
            sum += e;
        }
    sum += __shfl_xor(sum, 16, 64);
    sum += __shfl_xor(sum, 32, 64);
    const float rs = 1.0f / sum;

    // PV in two 128-kv chunks: normalized P^T -> sPT -> A-frags; V from ws
    f32x4 o0 = vzero, o1 = vzero;
#pragma unroll
    for (int c = 0; c < 2; ++c) {
#pragma unroll
        for (int cc = 0; cc < 8; ++cc) {
            const int ct = c * 8 + cc;
            bf16x4_t pv;
#pragma unroll
            for (int r = 0; r < 4; ++r) pv[r] = f2bf(sv[ct][r] * rs);
            *(bf16x4_t*)&sPT[w][l16][cc * 16 + quad * 4] = pv;
        }
#pragma unroll
        for (int ks = 0; ks < 4; ++ks) {
            const bf16x8 ap = *(const bf16x8*)&sPT[w][l16][ks * 32 + quad * 8];
            const int cs = c * 4 + ks;
            const bf16x8 bv0 = *(const bf16x8*)&Vf[base + (size_t)(cs * 2 + 0) * 512 + lane * 8];
            const bf16x8 bv1 = *(const bf16x8*)&Vf[base + (size_t)(cs * 2 + 1) * 512 + lane * 8];
            o0 = mfma16(ap, bv0, o0);
            o1 = mfma16(ap, bv1, o1);
        }
    }
    // O tile (q=quad*4+r, d=nt*16+l16) -> Ows[s][h][tile][q][d] (aliases Qf;
    // qfr consumed above -> read-before-write within the wave)
    bf16_t* dst = &Ows[base + (size_t)tile * 512];
#pragma unroll
    for (int nt = 0; nt < 2; ++nt) {
        const f32x4 o = nt ? o1 : o0;
#pragma unroll
        for (int r = 0; r < 4; ++r)
            dst[(quad * 4 + r) * DH + nt * 16 + l16] = f2bf(o[r]);
    }
}

// ---------------------------------------------------------------------------
// Phase 3: barrier-free outproj consuming fragment-native WoF (r9-proven).
// 2048 one-wave blocks: 8 a-frags + 32 WoF frags (L2 broadcast) + 32 MFMA.
__launch_bounds__(64, 4)
__global__ void outproj3(const bf16_t* __restrict__ Ows, const bf16_t* __restrict__ WoF,
                         const float* __restrict__ Bo, float* __restrict__ Out) {
    const int b = blockIdx.x;                 // m-tile index, 0..2047
    const int s = b >> 4, tile = b & 15;
    const int lane = threadIdx.x & 63;
    const int quad = lane >> 4, l16 = lane & 15;
    const f32x4 vzero = {0.f, 0.f, 0.f, 0.f};

    f32x4 acc[4];
#pragma unroll
    for (int nt = 0; nt < 4; ++nt) acc[nt] = vzero;
#pragma unroll
    for (int h = 0; h < NH; ++h) {
        const bf16x8 a = *(const bf16x8*)&Ows[((size_t)(s * NH + h) * 16 + tile) * 512 +
                                              l16 * DH + quad * 8];
#pragma unroll
        for (int nt = 0; nt < 4; ++nt) {
            const bf16x8 bwo = *(const bf16x8*)&WoF[(size_t)(h * 4 + nt) * 512 + lane * 8];
            acc[nt] = mfma16(a, bwo, acc[nt]);
        }
    }
    const int mr0 = b * 16;
#pragma unroll
    for (int nt = 0; nt < 4; ++nt) {
        const float bo = Bo[nt * 16 + l16];
#pragma unroll
        for (int r = 0; r < 4; ++r)
            Out[(mr0 + quad * 4 + r) * CIN + nt * 16 + l16] = acc[nt][r] + bo;
    }
}

// ---------------------------------------------------------------------------
// Phase 3 fallback: staged Wo (used only if ws lacks WoF room).
__launch_bounds__(256, 4)
__global__ void outproj2(const bf16_t* __restrict__ Ows, const float* __restrict__ Wo,
                         const float* __restrict__ Bo, float* __restrict__ Out) {
    const int tid = threadIdx.x, lane = tid & 63, w = tid >> 6;
    const int quad = lane >> 4, l16 = lane & 15;
    const int R = blockIdx.x * 128;
    const int s = R >> 8;

    __shared__ __attribute__((aligned(16))) bf16_t sWoT[CIN][HD + 8];
    __shared__ float sBo[CIN];

#pragma unroll
    for (int it = 0; it < 16; ++it) {
        const int idx = it * 256 + tid;
        const int kk = idx >> 4, c4 = (idx & 15) << 2;
        const f32x4 w4 = *(const f32x4*)&Wo[kk * CIN + c4];
#pragma unroll
        for (int j = 0; j < 4; ++j) sWoT[c4 + j][kk] = f2bf(w4[j]);
    }
    if (tid < CIN) sBo[tid] = Bo[tid];
    __syncthreads();

    const f32x4 vzero = {0.f, 0.f, 0.f, 0.f};
#pragma unroll 1
    for (int i = 0; i < 2; ++i) {
        const int mr0 = R + w * 32 + i * 16;
        const int tile = (mr0 & 255) >> 4;
        bf16x8 a[8];
#pragma unroll
        for (int ks = 0; ks < 8; ++ks)
            a[ks] = *(const bf16x8*)&Ows[((size_t)(s * NH + ks) * 16 + tile) * 512 +
                                         l16 * DH + quad * 8];
        f32x4 acc[4];
#pragma unroll
        for (int nt = 0; nt < 4; ++nt) acc[nt] = vzero;
#pragma unroll
        for (int ks = 0; ks < 8; ++ks)
#pragma unroll
            for (int nt = 0; nt < 4; ++nt) {
                const bf16x8 bb = *(const bf16x8*)&sWoT[nt * 16 + l16][ks * 32 + quad * 8];
                acc[nt] = mfma16(a[ks], bb, acc[nt]);
            }
#pragma unroll
        for (int nt = 0; nt < 4; ++nt) {
            const float bo = sBo[nt * 16 + l16];
#pragma unroll
            for (int r = 0; r < 4; ++r)
                Out[(mr0 + quad * 4 + r) * CIN + nt * 16 + l16] = acc[nt][r] + bo;
        }
    }
}

extern "C" void kernel_launch(void* const* d_in, const int* in_sizes, int n_in,
                              void* d_out, int out_size, void* d_ws, size_t ws_size,
                              hipStream_t stream) {
    const float* Xq   = (const float*)d_in[0];
    const float* Xkv  = (const float*)d_in[1];
    const float* Mask = (const float*)d_in[2];
    const float* Bias = (const float*)d_in[3];
    const float* Wq   = (const float*)d_in[4];
    const float* Wk   = (const float*)d_in[5];
    const float* Wv   = (const float*)d_in[6];
    const float* Wo   = (const float*)d_in[7];
    const float* Bo   = (const float*)d_in[8];
    float* Out = (float*)d_out;

    const size_t SEG = 16777216;  // 16 MiB; ws >= 48 MiB proven in r5-r11
    bf16_t* Qf  = (bf16_t*)d_ws;
    bf16_t* Kf  = (bf16_t*)((char*)d_ws + SEG);
    bf16_t* Vf  = (bf16_t*)((char*)d_ws + 2 * SEG);
    bf16_t* Ows = Qf;  // aliased: per-(s,h,tile) read-before-write within one wave
    const bool haveWoF = ws_size >= 3 * SEG + 32768;
    bf16_t* WoF = haveWoF ? (bf16_t*)((char*)d_ws + 3 * SEG) : nullptr;

    projt<<<3072, 64, 0, stream>>>(Xq, Xkv, Wq, Wk, Wv, Wo, Qf, Kf, Vf, WoF);
    attn3<<<dim3(128, 4, NH), 256, 0, stream>>>(Mask, Bias, Qf, Kf, Vf, Ows);
    if (haveWoF)
        outproj3<<<2048, 64, 0, stream>>>(Ows, WoF, Bo, Out);
    else
        outproj2<<<256, 256, 0, stream>>>(Ows, Wo, Bo, Out);
}

// Round 13
// 152.428 us; speedup vs baseline: 1.2744x; 1.2744x over previous
//
#include <hip/hip_runtime.h>

typedef __bf16 bf16_t;
typedef __bf16 bf16x4_t __attribute__((ext_vector_type(4)));
typedef __bf16 bf16x8 __attribute__((ext_vector_type(8)));
typedef float f32x4 __attribute__((ext_vector_type(4)));

#define NH 8
#define DH 32
#define QL 256
#define KL 256
#define CIN 64
#define HD 256  // NH*DH

__device__ __forceinline__ bf16_t f2bf(float x) { return (bf16_t)x; }

__device__ __forceinline__ f32x4 mfma16(bf16x8 a, bf16x8 b, f32x4 c) {
    return __builtin_amdgcn_mfma_f32_16x16x32_bf16(a, b, c, 0, 0, 0);
}

// ---------------------------------------------------------------------------
// Phase 1 (proj_s): grid (which, s) = 384 blocks x 4 waves. The s's X slice
// is staged ONCE into LDS via coalesced f32x4 loads (r12 lesson: the ~85 µs
// proj cost was strided global A-frag reads re-issued per head, not TLP).
// All A-frags then come from ds_read_b128 (rows padded to 72 bf16 -> 2-way
// banks, free). W B-frags: per-head scalar gathers (L2-hot), 2 heads/wave,
// amortized over that head's 16 tile-tasks. Q pre-scaled at staging.
//   Qf/Kf per (s,h): 16 tiles x [lane][8], elem = M[tile*16+l16][quad*8+j]
//   Vf  per (s,h): 16 chunks x [lane][8],  elem = V[cs*32+quad*8+j][nt*16+l16]
//   WoF: (h*4+nt) x [lane][8], elem = Wo[h*32+quad*8+j][nt*16+l16]
__launch_bounds__(256, 2)
__global__ void proj_s(const float* __restrict__ Xq, const float* __restrict__ Xkv,
                       const float* __restrict__ Wq, const float* __restrict__ Wk,
                       const float* __restrict__ Wv, const float* __restrict__ Wo,
                       bf16_t* __restrict__ Qf, bf16_t* __restrict__ Kf,
                       bf16_t* __restrict__ Vf, bf16_t* __restrict__ WoF) {
    const int b = blockIdx.x;
    const int s = b & 127, which = b >> 7;  // s fastest: XCD = s&7 (matches attn3)
    const int tid = threadIdx.x, lane = tid & 63, w = tid >> 6;
    const int quad = lane >> 4, l16 = lane & 15;
    const f32x4 vzero = {0.f, 0.f, 0.f, 0.f};

    __shared__ __attribute__((aligned(16))) bf16_t sX[QL][72];       // 36.9 KB
    __shared__ __attribute__((aligned(16))) bf16_t sT[4][2][32][40]; // 20.5 KB dbuf

    const float* __restrict__ X = (which == 0) ? Xq : Xkv;
    const float* __restrict__ W = (which == 0) ? Wq : (which == 1 ? Wk : Wv);
    const float scale = (which == 0) ? 0.17677669529663687f : 1.0f;  // 1/sqrt(32)

    // ---- stage X slice (coalesced f32x4; 16 per thread), Q pre-scaled ----
#pragma unroll
    for (int it = 0; it < 16; ++it) {
        const int idx = it * 256 + tid;
        const int row = idx >> 4, c4 = (idx & 15) << 2;
        const f32x4 x4 = *(const f32x4*)&X[(s * QL + row) * CIN + c4];
#pragma unroll
        for (int j = 0; j < 4; ++j) sX[row][c4 + j] = f2bf(x4[j] * scale);
    }
    __syncthreads();

    // 8 special waves (which==1, s==0) also emit Wo fragment-native
    if (which == 1 && s == 0 && WoF != nullptr) {
#pragma unroll
        for (int hh = 0; hh < 2; ++hh) {
            const int h = w * 2 + hh;
#pragma unroll
            for (int nt = 0; nt < 4; ++nt) {
                bf16x8 f;
#pragma unroll
                for (int j = 0; j < 8; ++j)
                    f[j] = f2bf(Wo[(h * DH + quad * 8 + j) * CIN + nt * 16 + l16]);
                *(bf16x8*)&WoF[(size_t)(h * 4 + nt) * 512 + lane * 8] = f;
            }
        }
    }

    // ---- wave w handles heads {2w, 2w+1} ----
#pragma unroll 1
    for (int hh = 0; hh < 2; ++hh) {
        const int h = w * 2 + hh;
        // W B-frags via scalar gathers: bw[nt][ks][j] = W[ks*32+quad*8+j][h*32+nt*16+l16]
        bf16x8 bw[2][2];
#pragma unroll
        for (int nt = 0; nt < 2; ++nt)
#pragma unroll
            for (int ks = 0; ks < 2; ++ks) {
                bf16x8 f;
#pragma unroll
                for (int j = 0; j < 8; ++j)
                    f[j] = f2bf(W[(ks * 32 + quad * 8 + j) * HD + h * DH + nt * 16 + l16]);
                bw[nt][ks] = f;
            }
        const size_t base = (size_t)(s * NH + h) * 8192;

        if (which < 2) {
            bf16_t* __restrict__ Dst = which ? Kf : Qf;
            // 16 independent tile-tasks; A-frags from LDS (b128, 2-way banks)
#pragma unroll 2
            for (int mt = 0; mt < 16; ++mt) {
                const bf16x8 a0 = *(const bf16x8*)&sX[mt * 16 + l16][quad * 8];
                const bf16x8 a1 = *(const bf16x8*)&sX[mt * 16 + l16][32 + quad * 8];
                f32x4 c0 = vzero, c1 = vzero;
                c0 = mfma16(a0, bw[0][0], c0);
                c0 = mfma16(a1, bw[0][1], c0);
                c1 = mfma16(a0, bw[1][0], c1);
                c1 = mfma16(a1, bw[1][1], c1);
                // C/D (row=quad*4+r, d=nt*16+l16) -> sT -> A-frag (same-wave RT)
#pragma unroll
                for (int nt = 0; nt < 2; ++nt) {
                    const f32x4 c = nt ? c1 : c0;
#pragma unroll
                    for (int r = 0; r < 4; ++r)
                        sT[w][mt & 1][quad * 4 + r][nt * 16 + l16] = f2bf(c[r]);
                }
                const bf16x8 frag = *(const bf16x8*)&sT[w][mt & 1][l16][quad * 8];
                *(bf16x8*)&Dst[base + (size_t)mt * 512 + lane * 8] = frag;
            }
        } else {
            // 8 independent 32-kv chunk tasks
#pragma unroll 2
            for (int cs = 0; cs < 8; ++cs) {
                bf16x8 a[2][2];
#pragma unroll
                for (int u = 0; u < 2; ++u) {
                    a[u][0] = *(const bf16x8*)&sX[cs * 32 + u * 16 + l16][quad * 8];
                    a[u][1] = *(const bf16x8*)&sX[cs * 32 + u * 16 + l16][32 + quad * 8];
                }
                // C/D (kv=u*16+quad*4+r, d=nth*16+l16) -> sT[d][kv] (transposed)
#pragma unroll
                for (int u = 0; u < 2; ++u)
#pragma unroll
                    for (int nth = 0; nth < 2; ++nth) {
                        f32x4 c = mfma16(a[u][0], bw[nth][0], vzero);
                        c = mfma16(a[u][1], bw[nth][1], c);
#pragma unroll
                        for (int r = 0; r < 4; ++r)
                            sT[w][cs & 1][nth * 16 + l16][u * 16 + quad * 4 + r] = f2bf(c[r]);
                    }
#pragma unroll
                for (int nt = 0; nt < 2; ++nt) {
                    const bf16x8 frag = *(const bf16x8*)&sT[w][cs & 1][nt * 16 + l16][quad * 8];
                    *(bf16x8*)&Vf[base + (size_t)(cs * 2 + nt) * 512 + lane * 8] = frag;
                }
            }
        }
    }
}

// ---------------------------------------------------------------------------
// Phase 2: attention, barrier-free pure consumer. EXACTLY the r9-proven
// occupancy config (256,4): 128-VGPR budget, VGPR 56, no spill — r8/r12
// both showed tighter budgets spill sv[16] at 6-10x WRITE cost.
__launch_bounds__(256, 4)
__global__ void attn3(const float* __restrict__ Mask, const float* __restrict__ Bias,
                      const bf16_t* __restrict__ Qf, const bf16_t* __restrict__ Kf,
                      const bf16_t* __restrict__ Vf, bf16_t* __restrict__ Ows) {
    const int s = blockIdx.x, qt = blockIdx.y, h = blockIdx.z;
    const int tid = threadIdx.x, lane = tid & 63, w = tid >> 6;
    const int quad = lane >> 4, l16 = lane & 15;
    const f32x4 vzero = {0.f, 0.f, 0.f, 0.f};

    __shared__ __attribute__((aligned(16))) bf16_t sPT[4][16][136];  // 17.4 KB

    const int tile = qt * 4 + w, q0 = tile * 16;
    const size_t base = (size_t)(s * NH + h) * 8192;

    const bf16x8 qfr = *(const bf16x8*)&Qf[base + (size_t)tile * 512 + lane * 8];

    // sv = bias + mask (loads issue early), then S' = K·Q^T rides C operand
    f32x4 sv[16];
    const float* bbase = &Bias[(size_t)(h * QL + q0 + l16) * KL];
    const float* mbase = &Mask[s * KL];
#pragma unroll
    for (int ct = 0; ct < 16; ++ct) {
        const f32x4 b4 = *(const f32x4*)&bbase[ct * 16 + quad * 4];
        const f32x4 m4 = *(const f32x4*)&mbase[ct * 16 + quad * 4];
        sv[ct] = b4 + (m4 - 1.0f) * 1.0e9f;
    }
#pragma unroll
    for (int ct = 0; ct < 16; ++ct) {
        const bf16x8 ak = *(const bf16x8*)&Kf[base + ct * 512 + lane * 8];
        sv[ct] = mfma16(ak, qfr, sv[ct]);  // C/D row=kv-local, col=q
    }
    // softmax over kv: per-lane 64 values + xor 16/32 across quads
    float mx = -1e30f;
#pragma unroll
    for (int ct = 0; ct < 16; ++ct)
#pragma unroll
        for (int r = 0; r < 4; ++r) mx = fmaxf(mx, sv[ct][r]);
    mx = fmaxf(mx, __shfl_xor(mx, 16, 64));
    mx = fmaxf(mx, __shfl_xor(mx, 32, 64));
    float sum = 0.f;
#pragma unroll
    for (int ct = 0; ct < 16; ++ct)
#pragma unroll
        for (int r = 0; r < 4; ++r) {
            const float e = __expf(sv[ct][r] - mx);
            sv[ct][r] = e;
            sum += e;
        }
    sum += __shfl_xor(sum, 16, 64);
    sum += __shfl_xor(sum, 32, 64);
    const float rs = 1.0f / sum;

    // PV in two 128-kv chunks: normalized P^T -> sPT -> A-frags; V from ws
    f32x4 o0 = vzero, o1 = vzero;
#pragma unroll
    for (int c = 0; c < 2; ++c) {
#pragma unroll
        for (int cc = 0; cc < 8; ++cc) {
            const int ct = c * 8 + cc;
            bf16x4_t pv;
#pragma unroll
            for (int r = 0; r < 4; ++r) pv[r] = f2bf(sv[ct][r] * rs);
            *(bf16x4_t*)&sPT[w][l16][cc * 16 + quad * 4] = pv;
        }
#pragma unroll
        for (int ks = 0; ks < 4; ++ks) {
            const bf16x8 ap = *(const bf16x8*)&sPT[w][l16][ks * 32 + quad * 8];
            const int cs = c * 4 + ks;
            const bf16x8 bv0 = *(const bf16x8*)&Vf[base + (size_t)(cs * 2 + 0) * 512 + lane * 8];
            const bf16x8 bv1 = *(const bf16x8*)&Vf[base + (size_t)(cs * 2 + 1) * 512 + lane * 8];
            o0 = mfma16(ap, bv0, o0);
            o1 = mfma16(ap, bv1, o1);
        }
    }
    // O tile (q=quad*4+r, d=nt*16+l16) -> Ows[s][h][tile][q][d] (aliases Qf;
    // qfr consumed above -> read-before-write within the wave)
    bf16_t* dst = &Ows[base + (size_t)tile * 512];
#pragma unroll
    for (int nt = 0; nt < 2; ++nt) {
        const f32x4 o = nt ? o1 : o0;
#pragma unroll
        for (int r = 0; r < 4; ++r)
            dst[(quad * 4 + r) * DH + nt * 16 + l16] = f2bf(o[r]);
    }
}

// ---------------------------------------------------------------------------
// Phase 3: barrier-free outproj consuming fragment-native WoF (r9-proven).
__launch_bounds__(64, 4)
__global__ void outproj3(const bf16_t* __restrict__ Ows, const bf16_t* __restrict__ WoF,
                         const float* __restrict__ Bo, float* __restrict__ Out) {
    const int b = blockIdx.x;                 // m-tile index, 0..2047
    const int s = b >> 4, tile = b & 15;
    const int lane = threadIdx.x & 63;
    const int quad = lane >> 4, l16 = lane & 15;
    const f32x4 vzero = {0.f, 0.f, 0.f, 0.f};

    f32x4 acc[4];
#pragma unroll
    for (int nt = 0; nt < 4; ++nt) acc[nt] = vzero;
#pragma unroll
    for (int h = 0; h < NH; ++h) {
        const bf16x8 a = *(const bf16x8*)&Ows[((size_t)(s * NH + h) * 16 + tile) * 512 +
                                              l16 * DH + quad * 8];
#pragma unroll
        for (int nt = 0; nt < 4; ++nt) {
            const bf16x8 bwo = *(const bf16x8*)&WoF[(size_t)(h * 4 + nt) * 512 + lane * 8];
            acc[nt] = mfma16(a, bwo, acc[nt]);
        }
    }
    const int mr0 = b * 16;
#pragma unroll
    for (int nt = 0; nt < 4; ++nt) {
        const float bo = Bo[nt * 16 + l16];
#pragma unroll
        for (int r = 0; r < 4; ++r)
            Out[(mr0 + quad * 4 + r) * CIN + nt * 16 + l16] = acc[nt][r] + bo;
    }
}

// ---------------------------------------------------------------------------
// Phase 3 fallback: staged Wo (used only if ws lacks WoF room).
__launch_bounds__(256, 4)
__global__ void outproj2(const bf16_t* __restrict__ Ows, const float* __restrict__ Wo,
                         const float* __restrict__ Bo, float* __restrict__ Out) {
    const int tid = threadIdx.x, lane = tid & 63, w = tid >> 6;
    const int quad = lane >> 4, l16 = lane & 15;
    const int R = blockIdx.x * 128;
    const int s = R >> 8;

    __shared__ __attribute__((aligned(16))) bf16_t sWoT[CIN][HD + 8];
    __shared__ float sBo[CIN];

#pragma unroll
    for (int it = 0; it < 16; ++it) {
        const int idx = it * 256 + tid;
        const int kk = idx >> 4, c4 = (idx & 15) << 2;
        const f32x4 w4 = *(const f32x4*)&Wo[kk * CIN + c4];
#pragma unroll
        for (int j = 0; j < 4; ++j) sWoT[c4 + j][kk] = f2bf(w4[j]);
    }
    if (tid < CIN) sBo[tid] = Bo[tid];
    __syncthreads();

    const f32x4 vzero = {0.f, 0.f, 0.f, 0.f};
#pragma unroll 1
    for (int i = 0; i < 2; ++i) {
        const int mr0 = R + w * 32 + i * 16;
        const int tile = (mr0 & 255) >> 4;
        bf16x8 a[8];
#pragma unroll
        for (int ks = 0; ks < 8; ++ks)
            a[ks] = *(const bf16x8*)&Ows[((size_t)(s * NH + ks) * 16 + tile) * 512 +
                                         l16 * DH + quad * 8];
        f32x4 acc[4];
#pragma unroll
        for (int nt = 0; nt < 4; ++nt) acc[nt] = vzero;
#pragma unroll
        for (int ks = 0; ks < 8; ++ks)
#pragma unroll
            for (int nt = 0; nt < 4; ++nt) {
                const bf16x8 bb = *(const bf16x8*)&sWoT[nt * 16 + l16][ks * 32 + quad * 8];
                acc[nt] = mfma16(a[ks], bb, acc[nt]);
            }
#pragma unroll
        for (int nt = 0; nt < 4; ++nt) {
            const float bo = sBo[nt * 16 + l16];
#pragma unroll
            for (int r = 0; r < 4; ++r)
                Out[(mr0 + quad * 4 + r) * CIN + nt * 16 + l16] = acc[nt][r] + bo;
        }
    }
}

extern "C" void kernel_launch(void* const* d_in, const int* in_sizes, int n_in,
                              void* d_out, int out_size, void* d_ws, size_t ws_size,
                              hipStream_t stream) {
    const float* Xq   = (const float*)d_in[0];
    const float* Xkv  = (const float*)d_in[1];
    const float* Mask = (const float*)d_in[2];
    const float* Bias = (const float*)d_in[3];
    const float* Wq   = (const float*)d_in[4];
    const float* Wk   = (const float*)d_in[5];
    const float* Wv   = (const float*)d_in[6];
    const float* Wo   = (const float*)d_in[7];
    const float* Bo   = (const float*)d_in[8];
    float* Out = (float*)d_out;

    const size_t SEG = 16777216;  // 16 MiB; ws >= 48 MiB proven in r5-r12
    bf16_t* Qf  = (bf16_t*)d_ws;
    bf16_t* Kf  = (bf16_t*)((char*)d_ws + SEG);
    bf16_t* Vf  = (bf16_t*)((char*)d_ws + 2 * SEG);
    bf16_t* Ows = Qf;  // aliased: per-(s,h,tile) read-before-write within one wave
    const bool haveWoF = ws_size >= 3 * SEG + 32768;
    bf16_t* WoF = haveWoF ? (bf16_t*)((char*)d_ws + 3 * SEG) : nullptr;

    proj_s<<<384, 256, 0, stream>>>(Xq, Xkv, Wq, Wk, Wv, Wo, Qf, Kf, Vf, WoF);
    attn3<<<dim3(128, 4, NH), 256, 0, stream>>>(Mask, Bias, Qf, Kf, Vf, Ows);
    if (haveWoF)
        outproj3<<<2048, 64, 0, stream>>>(Ows, WoF, Bo, Out);
    else
        outproj2<<<256, 256, 0, stream>>>(Ows, Wo, Bo, Out);
}